// Round 1
// baseline (8871.558 us; speedup 1.0000x reference)
//
#include <hip/hip_runtime.h>
#include <hip/hip_bf16.h>

namespace {

constexpr int T_ = 96;
constexpr int D_ = 16;
constexpr int H_ = 128;

__device__ __forceinline__ float sig_(float x) { return 1.f / (1.f + __expf(-x)); }
__device__ __forceinline__ float tanh_(float x) { return 1.f - 2.f / (__expf(2.f * x) + 1.f); }

// ---------------------------------------------------------------------------
// K1: two-layer LSTM. Block = 512 threads handles 16 sequences for all 96
// steps. Thread (j = tid&127, sg = tid>>7) owns hidden unit j for 4 seqs:
// computes gate rows j, j+128, j+256, j+384 (i,f,g,o), keeps c in registers,
// h in double-buffered LDS. h2 history -> global ws as bf16.
// ---------------------------------------------------------------------------
__global__ __launch_bounds__(512) void k1_lstm(
    const float* __restrict__ x,
    const float* __restrict__ Wih0, const float* __restrict__ Whh0,
    const float* __restrict__ bih0, const float* __restrict__ bhh0,
    const float* __restrict__ Wih1, const float* __restrict__ Whh1,
    const float* __restrict__ bih1, const float* __restrict__ bhh1,
    __hip_bfloat16* __restrict__ hist)
{
  __shared__ float h1s[2][16][H_];
  __shared__ float h2s[2][16][H_];
  __shared__ float xbuf[16][D_];
  const int tid = threadIdx.x;
  const int j = tid & 127;
  const int sg = tid >> 7;
  const int s0 = sg * 4;
  const int seqbase = blockIdx.x * 16;

  for (int i = tid; i < 2 * 16 * H_; i += 512) {
    (&h1s[0][0][0])[i] = 0.f;
    (&h2s[0][0][0])[i] = 0.f;
  }
  float c1[4] = {0.f, 0.f, 0.f, 0.f}, c2[4] = {0.f, 0.f, 0.f, 0.f};
  float bias0[4], bias1[4];
  const float *pW0x[4], *pW0h[4], *pW1x[4], *pW1h[4];
#pragma unroll
  for (int r = 0; r < 4; ++r) {
    const int row = j + 128 * r;
    bias0[r] = bih0[row] + bhh0[row];
    bias1[r] = bih1[row] + bhh1[row];
    pW0x[r] = Wih0 + (size_t)row * D_;
    pW0h[r] = Whh0 + (size_t)row * H_;
    pW1x[r] = Wih1 + (size_t)row * H_;
    pW1h[r] = Whh1 + (size_t)row * H_;
  }
  int cur = 0;
  __syncthreads();

  for (int t = 0; t < T_; ++t) {
    if (tid < 64) {
      const int s = tid >> 2, d4 = (tid & 3) * 4;
      *reinterpret_cast<float4*>(&xbuf[s][d4]) =
          *reinterpret_cast<const float4*>(x + ((size_t)(seqbase + s) * T_ + t) * D_ + d4);
    }
    __syncthreads();

    // ---- layer 0: gates = Wih0 @ x_t + Whh0 @ h1 + bias
    float acc[4][4];
#pragma unroll
    for (int r = 0; r < 4; ++r) {
#pragma unroll
      for (int s = 0; s < 4; ++s) acc[r][s] = bias0[r];
    }
#pragma unroll
    for (int kk = 0; kk < D_ / 4; ++kk) {
      float4 w[4];
#pragma unroll
      for (int r = 0; r < 4; ++r) w[r] = *reinterpret_cast<const float4*>(pW0x[r] + kk * 4);
#pragma unroll
      for (int s = 0; s < 4; ++s) {
        const float4 a = *reinterpret_cast<const float4*>(&xbuf[s0 + s][kk * 4]);
#pragma unroll
        for (int r = 0; r < 4; ++r)
          acc[r][s] += w[r].x * a.x + w[r].y * a.y + w[r].z * a.z + w[r].w * a.w;
      }
    }
#pragma unroll 4
    for (int kk = 0; kk < H_ / 4; ++kk) {
      float4 w[4];
#pragma unroll
      for (int r = 0; r < 4; ++r) w[r] = *reinterpret_cast<const float4*>(pW0h[r] + kk * 4);
#pragma unroll
      for (int s = 0; s < 4; ++s) {
        const float4 a = *reinterpret_cast<const float4*>(&h1s[cur][s0 + s][kk * 4]);
#pragma unroll
        for (int r = 0; r < 4; ++r)
          acc[r][s] += w[r].x * a.x + w[r].y * a.y + w[r].z * a.z + w[r].w * a.w;
      }
    }
    const int nxt = cur ^ 1;
#pragma unroll
    for (int s = 0; s < 4; ++s) {
      const float iv = sig_(acc[0][s]);
      const float fv = sig_(acc[1][s]);
      const float gv = tanh_(acc[2][s]);
      const float ov = sig_(acc[3][s]);
      c1[s] = fv * c1[s] + iv * gv;
      h1s[nxt][s0 + s][j] = ov * tanh_(c1[s]);
    }
    __syncthreads();

    // ---- layer 1: gates = Wih1 @ h1_new + Whh1 @ h2 + bias
#pragma unroll
    for (int r = 0; r < 4; ++r) {
#pragma unroll
      for (int s = 0; s < 4; ++s) acc[r][s] = bias1[r];
    }
#pragma unroll 4
    for (int kk = 0; kk < H_ / 4; ++kk) {
      float4 w[4];
#pragma unroll
      for (int r = 0; r < 4; ++r) w[r] = *reinterpret_cast<const float4*>(pW1x[r] + kk * 4);
#pragma unroll
      for (int s = 0; s < 4; ++s) {
        const float4 a = *reinterpret_cast<const float4*>(&h1s[nxt][s0 + s][kk * 4]);
#pragma unroll
        for (int r = 0; r < 4; ++r)
          acc[r][s] += w[r].x * a.x + w[r].y * a.y + w[r].z * a.z + w[r].w * a.w;
      }
    }
#pragma unroll 4
    for (int kk = 0; kk < H_ / 4; ++kk) {
      float4 w[4];
#pragma unroll
      for (int r = 0; r < 4; ++r) w[r] = *reinterpret_cast<const float4*>(pW1h[r] + kk * 4);
#pragma unroll
      for (int s = 0; s < 4; ++s) {
        const float4 a = *reinterpret_cast<const float4*>(&h2s[cur][s0 + s][kk * 4]);
#pragma unroll
        for (int r = 0; r < 4; ++r)
          acc[r][s] += w[r].x * a.x + w[r].y * a.y + w[r].z * a.z + w[r].w * a.w;
      }
    }
#pragma unroll
    for (int s = 0; s < 4; ++s) {
      const float iv = sig_(acc[0][s]);
      const float fv = sig_(acc[1][s]);
      const float gv = tanh_(acc[2][s]);
      const float ov = sig_(acc[3][s]);
      c2[s] = fv * c2[s] + iv * gv;
      const float hv = ov * tanh_(c2[s]);
      h2s[nxt][s0 + s][j] = hv;
      hist[((size_t)(seqbase + s0 + s) * T_ + t) * H_ + j] = __float2bfloat16(hv);
    }
    __syncthreads();
    cur = nxt;
  }
}

// ---------------------------------------------------------------------------
// K2: temporal attention pooling + LN1. One block (256 thr) per sequence.
// alpha[t] = tanh(h2[t]@W1 + hT@W2) . attn_w ; softmax over t; ctx; LN.
// ---------------------------------------------------------------------------
__global__ __launch_bounds__(256) void k2_pool(
    const __hip_bfloat16* __restrict__ hist,
    const float* __restrict__ attn_w,
    const float* __restrict__ W1,
    const float* __restrict__ W2,
    const float* __restrict__ ln1g, const float* __restrict__ ln1b,
    float* __restrict__ rep)
{
  const int n = blockIdx.x;
  const int tid = threadIdx.x;
  const int j = tid & 127;
  const int hh = tid >> 7;
  __shared__ float hTs[128], sS[128], aws[128];
  __shared__ float hst[16][128];
  __shared__ float up[16][128];
  __shared__ float sP[2][128];
  __shared__ float alpha[96];
  __shared__ float wts[96];
  __shared__ float red[128];

  const size_t base = (size_t)n * T_ * H_;
  if (tid < 128) {
    hTs[tid] = __bfloat162float(hist[base + (size_t)95 * H_ + tid]);
    aws[tid] = attn_w[tid];
  }
  __syncthreads();
  // s = hT @ W2 (split K over hh)
  {
    float sp = 0.f;
    for (int h = hh * 64; h < hh * 64 + 64; ++h) sp += hTs[h] * W2[(size_t)h * H_ + j];
    sP[hh][j] = sp;
  }
  __syncthreads();
  if (tid < 128) sS[j] = sP[0][j] + sP[1][j];
  __syncthreads();

  for (int p = 0; p < 6; ++p) {
    for (int i = tid; i < 16 * 128; i += 256) {
      const int tt = i >> 7, jj = i & 127;
      hst[tt][jj] = __bfloat162float(hist[base + (size_t)(p * 16 + tt) * H_ + jj]);
    }
    __syncthreads();
    float u[16];
#pragma unroll
    for (int tt = 0; tt < 16; ++tt) u[tt] = 0.f;
    for (int h0 = hh * 64; h0 < hh * 64 + 64; h0 += 4) {
      const float w0 = W1[(size_t)(h0 + 0) * H_ + j];
      const float w1 = W1[(size_t)(h0 + 1) * H_ + j];
      const float w2 = W1[(size_t)(h0 + 2) * H_ + j];
      const float w3 = W1[(size_t)(h0 + 3) * H_ + j];
#pragma unroll
      for (int tt = 0; tt < 16; ++tt) {
        const float4 a = *reinterpret_cast<const float4*>(&hst[tt][h0]);
        u[tt] += a.x * w0 + a.y * w1 + a.z * w2 + a.w * w3;
      }
    }
    if (hh == 1) {
#pragma unroll
      for (int tt = 0; tt < 16; ++tt) up[tt][j] = u[tt];
    }
    __syncthreads();
    if (hh == 0) {
#pragma unroll
      for (int tt = 0; tt < 16; ++tt) up[tt][j] += u[tt];
    }
    __syncthreads();
    {
      const int tt = tid >> 4, jl = tid & 15;
      float pa = 0.f;
#pragma unroll
      for (int qq = 0; qq < 8; ++qq) {
        const int q2 = jl * 8 + qq;
        pa += tanh_(up[tt][q2] + sS[q2]) * aws[q2];
      }
#pragma unroll
      for (int off = 8; off; off >>= 1) pa += __shfl_down(pa, off, 16);
      if (jl == 0) alpha[p * 16 + tt] = pa;
    }
    __syncthreads();
  }

  // softmax over 96 timesteps
  if (tid < 128) red[tid] = (tid < 96) ? alpha[tid] : -1e30f;
  __syncthreads();
  for (int sft = 64; sft > 0; sft >>= 1) {
    if (tid < sft) red[tid] = fmaxf(red[tid], red[tid + sft]);
    __syncthreads();
  }
  const float mx = red[0];
  __syncthreads();
  if (tid < 128) {
    const float e = (tid < 96) ? __expf(alpha[tid] - mx) : 0.f;
    red[tid] = e;
    if (tid < 96) wts[tid] = e;
  }
  __syncthreads();
  for (int sft = 64; sft > 0; sft >>= 1) {
    if (tid < sft) red[tid] += red[tid + sft];
    __syncthreads();
  }
  const float inv = 1.f / red[0];

  // ctx = sum_t w[t] * h2[t]
  {
    float cp = 0.f;
    for (int t = hh * 48; t < hh * 48 + 48; ++t)
      cp += wts[t] * __bfloat162float(hist[base + (size_t)t * H_ + j]);
    sP[hh][j] = cp * inv;
  }
  __syncthreads();
  if (tid < 128) hTs[tid] = sP[0][tid] + sP[1][tid];  // ctx now in hTs
  __syncthreads();
  // LN over 128
  if (tid < 128) red[tid] = hTs[tid];
  __syncthreads();
  for (int sft = 64; sft > 0; sft >>= 1) {
    if (tid < sft) red[tid] += red[tid + sft];
    __syncthreads();
  }
  const float mean = red[0] * (1.f / 128.f);
  __syncthreads();
  if (tid < 128) {
    const float d = hTs[tid] - mean;
    red[tid] = d * d;
  }
  __syncthreads();
  for (int sft = 64; sft > 0; sft >>= 1) {
    if (tid < sft) red[tid] += red[tid + sft];
    __syncthreads();
  }
  const float var = red[0] * (1.f / 128.f);
  if (tid < 128)
    rep[(size_t)n * H_ + tid] = (hTs[tid] - mean) * rsqrtf(var + 1e-5f) * ln1g[tid] + ln1b[tid];
}

// ---------------------------------------------------------------------------
// K3: xp = rep@projW+b ; q,k,v = xp@W+b. Block = 32 rows.
// ---------------------------------------------------------------------------
__global__ __launch_bounds__(256) void k3_qkv(
    const float* __restrict__ rep,
    const float* __restrict__ projW, const float* __restrict__ projb,
    const float* __restrict__ Wq, const float* __restrict__ bq,
    const float* __restrict__ Wk, const float* __restrict__ bk,
    const float* __restrict__ Wv, const float* __restrict__ bv,
    float* __restrict__ q, float* __restrict__ k, float* __restrict__ v)
{
  const int rbase = blockIdx.x * 32;
  const int tid = threadIdx.x;
  __shared__ float reps[32][128];
  __shared__ float xps[32][64];
  for (int i = tid; i < 32 * 128; i += 256)
    reps[i >> 7][i & 127] = rep[(size_t)(rbase + (i >> 7)) * 128 + (i & 127)];
  __syncthreads();
  const int col = tid & 63, rg = tid >> 6;
#pragma unroll 2
  for (int rr = 0; rr < 8; ++rr) {
    const int r = rg * 8 + rr;
    float acc = projb[col];
    for (int kk = 0; kk < 128; ++kk) acc += reps[r][kk] * projW[kk * 64 + col];
    xps[r][col] = acc;
  }
  __syncthreads();
#pragma unroll 2
  for (int rr = 0; rr < 8; ++rr) {
    const int r = rg * 8 + rr;
    float aq = bq[col], ak = bk[col], av = bv[col];
    for (int kk = 0; kk < 64; ++kk) {
      const float xv = xps[r][kk];
      aq += xv * Wq[kk * 64 + col];
      ak += xv * Wk[kk * 64 + col];
      av += xv * Wv[kk * 64 + col];
    }
    const size_t o = (size_t)(rbase + r) * 64 + col;
    q[o] = aq; k[o] = ak; v[o] = av;
  }
}

// ---------------------------------------------------------------------------
// K4: scores + rank-gate MLP + softmax + attn@v. One block per (b,n) row.
// ---------------------------------------------------------------------------
__global__ __launch_bounds__(128) void k4_attn(
    const float* __restrict__ q, const float* __restrict__ kbuf, const float* __restrict__ vbuf,
    const int* __restrict__ ranks, const float* __restrict__ rank_emb,
    const float* __restrict__ rw1W, const float* __restrict__ rw1b,
    const float* __restrict__ rw2W,
    float* __restrict__ ao)
{
  const int bn = blockIdx.x;  // b*128 + n
  const int b = bn >> 7;
  const int m = threadIdx.x;
  __shared__ float qs[64], attnw[128], red[128], aoP[2][64];
  if (m < 64) qs[m] = q[(size_t)bn * 64 + m];
  __syncthreads();
  const float* kr = kbuf + (size_t)(b * 128 + m) * 64;
  float sc = 0.f;
#pragma unroll 8
  for (int d = 0; d < 64; ++d) sc += qs[d] * kr[d];
  sc *= 0.125f;
  const int rn = ranks[bn], rm = ranks[b * 128 + m];
  int dist = rn - rm;
  if (dist < 0) dist = -dist;
  if (dist > 50) dist = 50;
  const float* er = rank_emb + dist * 32;
  float g = 0.f;
#pragma unroll
  for (int e = 0; e < 16; ++e) {
    float hs = rw1b[e];
#pragma unroll 8
    for (int i2 = 0; i2 < 32; ++i2) hs += er[i2] * rw1W[i2 * 16 + e];
    g += fmaxf(hs, 0.f) * rw2W[e];
  }
  const float smv = sc * sig_(g);
  red[m] = smv;
  __syncthreads();
  for (int sft = 64; sft > 0; sft >>= 1) {
    if (m < sft) red[m] = fmaxf(red[m], red[m + sft]);
    __syncthreads();
  }
  const float mx = red[0];
  __syncthreads();
  const float e = __expf(smv - mx);
  red[m] = e;
  __syncthreads();
  for (int sft = 64; sft > 0; sft >>= 1) {
    if (m < sft) red[m] += red[m + sft];
    __syncthreads();
  }
  attnw[m] = e / red[0];
  __syncthreads();
  const int d = m & 63, half = m >> 6;
  float acc = 0.f;
  for (int mm = half * 64; mm < half * 64 + 64; ++mm)
    acc += attnw[mm] * vbuf[(size_t)(b * 128 + mm) * 64 + d];
  aoP[half][d] = acc;
  __syncthreads();
  if (m < 64) ao[(size_t)bn * 64 + m] = aoP[0][m] + aoP[1][m];
}

// ---------------------------------------------------------------------------
// K5: ff = LN(relu(ao@ff1+b)@ff2+b) ; out = sigmoid(relu(ff@sp1+b)@sp2+b).
// One block per row.
// ---------------------------------------------------------------------------
__global__ __launch_bounds__(128) void k5_ffout(
    const float* __restrict__ ao,
    const float* __restrict__ ff1W, const float* __restrict__ ff1b,
    const float* __restrict__ ff2W, const float* __restrict__ ff2b,
    const float* __restrict__ ln2g, const float* __restrict__ ln2b,
    const float* __restrict__ sp1W, const float* __restrict__ sp1b,
    const float* __restrict__ sp2W, const float* __restrict__ sp2b,
    float* __restrict__ out)
{
  const int row = blockIdx.x;
  const int tid = threadIdx.x;
  __shared__ float aos[64], hid[128], ffs[64], red[128], h2b[32];
  if (tid < 64) aos[tid] = ao[(size_t)row * 64 + tid];
  __syncthreads();
  float hv = ff1b[tid];
  for (int dd = 0; dd < 64; ++dd) hv += aos[dd] * ff1W[dd * 128 + tid];
  hid[tid] = fmaxf(hv, 0.f);
  __syncthreads();
  float yv = 0.f;
  if (tid < 64) {
    yv = ff2b[tid];
    for (int h2 = 0; h2 < 128; ++h2) yv += hid[h2] * ff2W[h2 * 64 + tid];
  }
  red[tid] = (tid < 64) ? yv : 0.f;
  __syncthreads();
  for (int sft = 64; sft > 0; sft >>= 1) {
    if (tid < sft) red[tid] += red[tid + sft];
    __syncthreads();
  }
  const float mean = red[0] * (1.f / 64.f);
  __syncthreads();
  {
    const float d2 = (tid < 64) ? (yv - mean) : 0.f;
    red[tid] = d2 * d2;
  }
  __syncthreads();
  for (int sft = 64; sft > 0; sft >>= 1) {
    if (tid < sft) red[tid] += red[tid + sft];
    __syncthreads();
  }
  const float var = red[0] * (1.f / 64.f);
  __syncthreads();
  if (tid < 64) ffs[tid] = (yv - mean) * rsqrtf(var + 1e-5f) * ln2g[tid] + ln2b[tid];
  __syncthreads();
  if (tid < 32) {
    float h2v = sp1b[tid];
    for (int c = 0; c < 64; ++c) h2v += ffs[c] * sp1W[c * 32 + tid];
    h2b[tid] = fmaxf(h2v, 0.f);
  }
  __syncthreads();
  if (tid == 0) {
    float o = sp2b[0];
#pragma unroll
    for (int e2 = 0; e2 < 32; ++e2) o += h2b[e2] * sp2W[e2];
    out[row] = sig_(o);
  }
}

}  // namespace

extern "C" void kernel_launch(void* const* d_in, const int* in_sizes, int n_in,
                              void* d_out, int out_size, void* d_ws, size_t ws_size,
                              hipStream_t stream)
{
  const float* x      = (const float*)d_in[0];
  const int*   ranks  = (const int*)  d_in[1];
  const float* Wih0   = (const float*)d_in[2];
  const float* Whh0   = (const float*)d_in[3];
  const float* bih0   = (const float*)d_in[4];
  const float* bhh0   = (const float*)d_in[5];
  const float* Wih1   = (const float*)d_in[6];
  const float* Whh1   = (const float*)d_in[7];
  const float* bih1   = (const float*)d_in[8];
  const float* bhh1   = (const float*)d_in[9];
  const float* attn_w = (const float*)d_in[10];
  const float* W1     = (const float*)d_in[11];
  const float* W2     = (const float*)d_in[12];
  const float* ln1g   = (const float*)d_in[13];
  const float* ln1b   = (const float*)d_in[14];
  const float* projW  = (const float*)d_in[15];
  const float* projb  = (const float*)d_in[16];
  const float* Wq     = (const float*)d_in[17];
  const float* bq     = (const float*)d_in[18];
  const float* Wk     = (const float*)d_in[19];
  const float* bk     = (const float*)d_in[20];
  const float* Wv     = (const float*)d_in[21];
  const float* bv     = (const float*)d_in[22];
  const float* remb   = (const float*)d_in[23];
  const float* rw1W   = (const float*)d_in[24];
  const float* rw1b   = (const float*)d_in[25];
  const float* rw2W   = (const float*)d_in[26];
  const float* ff1W   = (const float*)d_in[27];
  const float* ff1b   = (const float*)d_in[28];
  const float* ff2W   = (const float*)d_in[29];
  const float* ff2b   = (const float*)d_in[30];
  const float* ln2g   = (const float*)d_in[31];
  const float* ln2b   = (const float*)d_in[32];
  const float* sp1W   = (const float*)d_in[33];
  const float* sp1b   = (const float*)d_in[34];
  const float* sp2W   = (const float*)d_in[35];
  const float* sp2b   = (const float*)d_in[36];
  float* out = (float*)d_out;

  char* ws = (char*)d_ws;
  __hip_bfloat16* hist = (__hip_bfloat16*)ws;            // 4096*96*128 bf16 = 96 MB
  size_t off = (size_t)4096 * 96 * 128 * 2;
  float* rep = (float*)(ws + off); off += (size_t)4096 * 128 * 4;
  float* qb  = (float*)(ws + off); off += (size_t)4096 * 64 * 4;
  float* kb  = (float*)(ws + off); off += (size_t)4096 * 64 * 4;
  float* vb  = (float*)(ws + off); off += (size_t)4096 * 64 * 4;
  float* aob = (float*)(ws + off); off += (size_t)4096 * 64 * 4;

  k1_lstm<<<dim3(256), dim3(512), 0, stream>>>(
      x, Wih0, Whh0, bih0, bhh0, Wih1, Whh1, bih1, bhh1, hist);
  k2_pool<<<dim3(4096), dim3(256), 0, stream>>>(
      hist, attn_w, W1, W2, ln1g, ln1b, rep);
  k3_qkv<<<dim3(128), dim3(256), 0, stream>>>(
      rep, projW, projb, Wq, bq, Wk, bk, Wv, bv, qb, kb, vb);
  k4_attn<<<dim3(4096), dim3(128), 0, stream>>>(
      qb, kb, vb, ranks, remb, rw1W, rw1b, rw2W, aob);
  k5_ffout<<<dim3(4096), dim3(128), 0, stream>>>(
      aob, ff1W, ff1b, ff2W, ff2b, ln2g, ln2b, sp1W, sp1b, sp2W, sp2b, out);
}

// Round 2
// 1115.170 us; speedup vs baseline: 7.9553x; 7.9553x over previous
//
#include <hip/hip_runtime.h>
#include <hip/hip_bf16.h>

namespace {

constexpr int T_ = 96;
constexpr int H_ = 128;

typedef short s8v __attribute__((ext_vector_type(8)));   // 8 bf16 (4 VGPR)
typedef float f4v __attribute__((ext_vector_type(4)));   // MFMA accumulator

__device__ __forceinline__ float sig_(float x) { return 1.f / (1.f + __expf(-x)); }
__device__ __forceinline__ float tanh_(float x) { return 1.f - 2.f / (__expf(2.f * x) + 1.f); }

__device__ __forceinline__ unsigned short bf16u(float f) {
  union { float f; unsigned u; } v; v.f = f;
  unsigned r = v.u + 0x7FFFu + ((v.u >> 16) & 1u);   // RNE
  return (unsigned short)(r >> 16);
}

__device__ __forceinline__ s8v load8(const float* __restrict__ p) {
  const float4 a = *reinterpret_cast<const float4*>(p);
  const float4 b = *reinterpret_cast<const float4*>(p + 4);
  s8v r;
  r[0] = (short)bf16u(a.x); r[1] = (short)bf16u(a.y);
  r[2] = (short)bf16u(a.z); r[3] = (short)bf16u(a.w);
  r[4] = (short)bf16u(b.x); r[5] = (short)bf16u(b.y);
  r[6] = (short)bf16u(b.z); r[7] = (short)bf16u(b.w);
  return r;
}

__device__ __forceinline__ f4v mfma16(s8v a, s8v b, f4v c) {
  return __builtin_amdgcn_mfma_f32_16x16x32_bf16(a, b, c, 0, 0, 0);
}

// LDS-only barrier: skip the vmcnt(0) drain __syncthreads() would emit
// (hist stores in flight must NOT stall the loop).
__device__ __forceinline__ void barrier_lds() {
  __builtin_amdgcn_sched_barrier(0);
  asm volatile("s_waitcnt lgkmcnt(0)" ::: "memory");
  __builtin_amdgcn_s_barrier();
  __builtin_amdgcn_sched_barrier(0);
}

// ---------------------------------------------------------------------------
// K1: two-layer LSTM via MFMA. Block = 512 thr (8 waves) owns 16 sequences.
// gates[16x512] = A(h[16x128] bf16) @ B(W^T, register-resident bf16 frags).
// Wave w owns N-tiles {4w..4w+3}. Per step: MFMA L0 -> nonlin L0 -> MFMA L1
// -> nonlin L1 (c state fp32 in regs; h re-quantized bf16 into swizzled LDS).
// ---------------------------------------------------------------------------
__global__ __launch_bounds__(512, 2) void k1_lstm_mfma(
    const float* __restrict__ x,
    const float* __restrict__ Wih0, const float* __restrict__ Whh0,
    const float* __restrict__ bih0, const float* __restrict__ bhh0,
    const float* __restrict__ Wih1, const float* __restrict__ Whh1,
    const float* __restrict__ bih1, const float* __restrict__ bhh1,
    unsigned short* __restrict__ hist)   // bf16 bits
{
  __shared__ __align__(16) unsigned short h1s[16 * 128];      // bf16, swizzled
  __shared__ __align__(16) unsigned short h2s[16 * 128];      // bf16, swizzled
  __shared__ __align__(16) unsigned short xb[16 * 32];        // bf16, k>=16 zero
  __shared__ __align__(16) float gates[16 * 516];             // padded stride
  __shared__ __align__(16) unsigned short w0frag[1024 * 8 + 8]; // Wih0 B-frags

  const int tid  = threadIdx.x;
  const int lane = tid & 63;
  const int wv   = tid >> 6;          // wave 0..7
  const int l16  = lane & 15;
  const int lq   = lane >> 4;         // 0..3
  const int seqbase = blockIdx.x * 16;

  // ---- init LDS
  for (int i = tid; i < 16 * 128; i += 512) { h1s[i] = 0; h2s[i] = 0; }
  for (int i = tid; i < 16 * 32; i += 512) xb[i] = 0;
  // Wih0 fragments: entry e=(ntg,l<32): lane l holds W[ntg*16+(l&15)][(l>>4)*8 + 0..7]
  for (int e = tid; e < 1024; e += 512) {
    const int ntg = e >> 5, l = e & 31;
    const float* p = Wih0 + (size_t)(ntg * 16 + (l & 15)) * 16 + (l >> 4) * 8;
    unsigned short* dst = &w0frag[e * 8];
#pragma unroll
    for (int i2 = 0; i2 < 8; ++i2) dst[i2] = bf16u(p[i2]);
  }
  if (tid < 8) w0frag[8192 + tid] = 0;  // zero slot (lanes 32-63 broadcast)

  // ---- register-resident recurrent weight fragments (B operand)
  // B[k][n] = W[n][k]: lane holds W[nt16+l16][kt*32 + lq*8 + 0..7]
  s8v whh0[4][4], wih1[4][4], whh1[4][4];
#pragma unroll
  for (int nt = 0; nt < 4; ++nt) {
    const int gr = (wv * 4 + nt) * 16 + l16;
#pragma unroll
    for (int kt = 0; kt < 4; ++kt) {
      const int k0 = kt * 32 + lq * 8;
      whh0[nt][kt] = load8(Whh0 + (size_t)gr * 128 + k0);
      wih1[nt][kt] = load8(Wih1 + (size_t)gr * 128 + k0);
      whh1[nt][kt] = load8(Whh1 + (size_t)gr * 128 + k0);
    }
  }

  // ---- nonlin-phase thread mapping: unit j, seqs s0+4*ss
  const int j  = tid & 127;
  const int s0 = tid >> 7;
  float b0[4], b1[4];
#pragma unroll
  for (int r = 0; r < 4; ++r) {
    b0[r] = bih0[j + 128 * r] + bhh0[j + 128 * r];
    b1[r] = bih1[j + 128 * r] + bhh1[j + 128 * r];
  }
  float c1[4] = {0.f, 0.f, 0.f, 0.f}, c2[4] = {0.f, 0.f, 0.f, 0.f};

  // x for t=0
  if (tid < 256) {
    const int s = tid >> 4, d = tid & 15;
    xb[s * 32 + d] = bf16u(x[((size_t)(seqbase + s) * T_ + 0) * 16 + d]);
  }
  __syncthreads();

  const int abase = l16 * 256;           // A-frag row base (bytes)
  const int sw    = (l16 & 7) << 4;      // XOR swizzle
  const int w0off = (lane < 32) ? (lane * 16) : 16384;  // + ntg*512

  for (int t = 0; t < T_; ++t) {
    f4v acc[4];
    // ================= P1: layer-0 MFMA =================
#pragma unroll
    for (int nt = 0; nt < 4; ++nt) acc[nt] = f4v{0.f, 0.f, 0.f, 0.f};
    {
      const s8v ax = *reinterpret_cast<const s8v*>(
          reinterpret_cast<const char*>(xb) + l16 * 64 + lq * 16);
#pragma unroll
      for (int nt = 0; nt < 4; ++nt) {
        const int ntg = wv * 4 + nt;
        const s8v bw = *reinterpret_cast<const s8v*>(
            reinterpret_cast<const char*>(w0frag) +
            ((lane < 32) ? ntg * 512 : 0) + w0off);
        acc[nt] = mfma16(ax, bw, acc[nt]);
      }
    }
#pragma unroll
    for (int kt = 0; kt < 4; ++kt) {
      const s8v ah = *reinterpret_cast<const s8v*>(
          reinterpret_cast<const char*>(h1s) + abase + ((kt * 64 + lq * 16) ^ sw));
#pragma unroll
      for (int nt = 0; nt < 4; ++nt) acc[nt] = mfma16(ah, whh0[nt][kt], acc[nt]);
    }
#pragma unroll
    for (int nt = 0; nt < 4; ++nt) {
      const int col = (wv * 4 + nt) * 16 + l16;
#pragma unroll
      for (int i2 = 0; i2 < 4; ++i2) gates[(lq * 4 + i2) * 516 + col] = acc[nt][i2];
    }
    barrier_lds();

    // ================= P2: layer-0 nonlinearity =================
#pragma unroll
    for (int ss = 0; ss < 4; ++ss) {
      const int s = s0 + ss * 4;
      const float gi = gates[s * 516 + j]       + b0[0];
      const float gf = gates[s * 516 + j + 128] + b0[1];
      const float gg = gates[s * 516 + j + 256] + b0[2];
      const float go = gates[s * 516 + j + 384] + b0[3];
      c1[ss] = sig_(gf) * c1[ss] + sig_(gi) * tanh_(gg);
      const float hv = sig_(go) * tanh_(c1[ss]);
      *reinterpret_cast<unsigned short*>(
          reinterpret_cast<char*>(h1s) + s * 256 + ((2 * j) ^ ((s & 7) << 4))) = bf16u(hv);
    }
    barrier_lds();

    // ================= P3: layer-1 MFMA =================
#pragma unroll
    for (int nt = 0; nt < 4; ++nt) acc[nt] = f4v{0.f, 0.f, 0.f, 0.f};
#pragma unroll
    for (int kt = 0; kt < 4; ++kt) {
      const s8v a1 = *reinterpret_cast<const s8v*>(
          reinterpret_cast<const char*>(h1s) + abase + ((kt * 64 + lq * 16) ^ sw));
#pragma unroll
      for (int nt = 0; nt < 4; ++nt) acc[nt] = mfma16(a1, wih1[nt][kt], acc[nt]);
    }
#pragma unroll
    for (int kt = 0; kt < 4; ++kt) {
      const s8v a2 = *reinterpret_cast<const s8v*>(
          reinterpret_cast<const char*>(h2s) + abase + ((kt * 64 + lq * 16) ^ sw));
#pragma unroll
      for (int nt = 0; nt < 4; ++nt) acc[nt] = mfma16(a2, whh1[nt][kt], acc[nt]);
    }
#pragma unroll
    for (int nt = 0; nt < 4; ++nt) {
      const int col = (wv * 4 + nt) * 16 + l16;
#pragma unroll
      for (int i2 = 0; i2 < 4; ++i2) gates[(lq * 4 + i2) * 516 + col] = acc[nt][i2];
    }
    barrier_lds();

    // ================= P4: layer-1 nonlinearity + hist + x prefetch =========
    if (t + 1 < T_ && tid < 256) {
      const int s = tid >> 4, d = tid & 15;
      xb[s * 32 + d] = bf16u(x[((size_t)(seqbase + s) * T_ + (t + 1)) * 16 + d]);
    }
#pragma unroll
    for (int ss = 0; ss < 4; ++ss) {
      const int s = s0 + ss * 4;
      const float gi = gates[s * 516 + j]       + b1[0];
      const float gf = gates[s * 516 + j + 128] + b1[1];
      const float gg = gates[s * 516 + j + 256] + b1[2];
      const float go = gates[s * 516 + j + 384] + b1[3];
      c2[ss] = sig_(gf) * c2[ss] + sig_(gi) * tanh_(gg);
      const float hv = sig_(go) * tanh_(c2[ss]);
      const unsigned short hb = bf16u(hv);
      *reinterpret_cast<unsigned short*>(
          reinterpret_cast<char*>(h2s) + s * 256 + ((2 * j) ^ ((s & 7) << 4))) = hb;
      hist[((size_t)(seqbase + s) * T_ + t) * H_ + j] = hb;
    }
    barrier_lds();
  }
}

// ---------------------------------------------------------------------------
// K2: temporal attention pooling + LN1. One block (256 thr) per sequence.
// ---------------------------------------------------------------------------
__global__ __launch_bounds__(256) void k2_pool(
    const __hip_bfloat16* __restrict__ hist,
    const float* __restrict__ attn_w,
    const float* __restrict__ W1,
    const float* __restrict__ W2,
    const float* __restrict__ ln1g, const float* __restrict__ ln1b,
    float* __restrict__ rep)
{
  const int n = blockIdx.x;
  const int tid = threadIdx.x;
  const int j = tid & 127;
  const int hh = tid >> 7;
  __shared__ float hTs[128], sS[128], aws[128];
  __shared__ float hst[16][128];
  __shared__ float up[16][128];
  __shared__ float sP[2][128];
  __shared__ float alpha[96];
  __shared__ float wts[96];
  __shared__ float red[128];

  const size_t base = (size_t)n * T_ * H_;
  if (tid < 128) {
    hTs[tid] = __bfloat162float(hist[base + (size_t)95 * H_ + tid]);
    aws[tid] = attn_w[tid];
  }
  __syncthreads();
  {
    float sp = 0.f;
    for (int h = hh * 64; h < hh * 64 + 64; ++h) sp += hTs[h] * W2[(size_t)h * H_ + j];
    sP[hh][j] = sp;
  }
  __syncthreads();
  if (tid < 128) sS[j] = sP[0][j] + sP[1][j];
  __syncthreads();

  for (int p = 0; p < 6; ++p) {
    for (int i = tid; i < 16 * 128; i += 256) {
      const int tt = i >> 7, jj = i & 127;
      hst[tt][jj] = __bfloat162float(hist[base + (size_t)(p * 16 + tt) * H_ + jj]);
    }
    __syncthreads();
    float u[16];
#pragma unroll
    for (int tt = 0; tt < 16; ++tt) u[tt] = 0.f;
    for (int h0 = hh * 64; h0 < hh * 64 + 64; h0 += 4) {
      const float w0 = W1[(size_t)(h0 + 0) * H_ + j];
      const float w1 = W1[(size_t)(h0 + 1) * H_ + j];
      const float w2 = W1[(size_t)(h0 + 2) * H_ + j];
      const float w3 = W1[(size_t)(h0 + 3) * H_ + j];
#pragma unroll
      for (int tt = 0; tt < 16; ++tt) {
        const float4 a = *reinterpret_cast<const float4*>(&hst[tt][h0]);
        u[tt] += a.x * w0 + a.y * w1 + a.z * w2 + a.w * w3;
      }
    }
    if (hh == 1) {
#pragma unroll
      for (int tt = 0; tt < 16; ++tt) up[tt][j] = u[tt];
    }
    __syncthreads();
    if (hh == 0) {
#pragma unroll
      for (int tt = 0; tt < 16; ++tt) up[tt][j] += u[tt];
    }
    __syncthreads();
    {
      const int tt = tid >> 4, jl = tid & 15;
      float pa = 0.f;
#pragma unroll
      for (int qq = 0; qq < 8; ++qq) {
        const int q2 = jl * 8 + qq;
        pa += tanh_(up[tt][q2] + sS[q2]) * aws[q2];
      }
#pragma unroll
      for (int off = 8; off; off >>= 1) pa += __shfl_down(pa, off, 16);
      if (jl == 0) alpha[p * 16 + tt] = pa;
    }
    __syncthreads();
  }

  if (tid < 128) red[tid] = (tid < 96) ? alpha[tid] : -1e30f;
  __syncthreads();
  for (int sft = 64; sft > 0; sft >>= 1) {
    if (tid < sft) red[tid] = fmaxf(red[tid], red[tid + sft]);
    __syncthreads();
  }
  const float mx = red[0];
  __syncthreads();
  if (tid < 128) {
    const float e = (tid < 96) ? __expf(alpha[tid] - mx) : 0.f;
    red[tid] = e;
    if (tid < 96) wts[tid] = e;
  }
  __syncthreads();
  for (int sft = 64; sft > 0; sft >>= 1) {
    if (tid < sft) red[tid] += red[tid + sft];
    __syncthreads();
  }
  const float inv = 1.f / red[0];

  {
    float cp = 0.f;
    for (int t = hh * 48; t < hh * 48 + 48; ++t)
      cp += wts[t] * __bfloat162float(hist[base + (size_t)t * H_ + j]);
    sP[hh][j] = cp * inv;
  }
  __syncthreads();
  if (tid < 128) hTs[tid] = sP[0][tid] + sP[1][tid];
  __syncthreads();
  if (tid < 128) red[tid] = hTs[tid];
  __syncthreads();
  for (int sft = 64; sft > 0; sft >>= 1) {
    if (tid < sft) red[tid] += red[tid + sft];
    __syncthreads();
  }
  const float mean = red[0] * (1.f / 128.f);
  __syncthreads();
  if (tid < 128) {
    const float d = hTs[tid] - mean;
    red[tid] = d * d;
  }
  __syncthreads();
  for (int sft = 64; sft > 0; sft >>= 1) {
    if (tid < sft) red[tid] += red[tid + sft];
    __syncthreads();
  }
  const float var = red[0] * (1.f / 128.f);
  if (tid < 128)
    rep[(size_t)n * H_ + tid] = (hTs[tid] - mean) * rsqrtf(var + 1e-5f) * ln1g[tid] + ln1b[tid];
}

// ---------------------------------------------------------------------------
// K3: xp = rep@projW+b ; q,k,v = xp@W+b. Block = 32 rows.
// ---------------------------------------------------------------------------
__global__ __launch_bounds__(256) void k3_qkv(
    const float* __restrict__ rep,
    const float* __restrict__ projW, const float* __restrict__ projb,
    const float* __restrict__ Wq, const float* __restrict__ bq,
    const float* __restrict__ Wk, const float* __restrict__ bk,
    const float* __restrict__ Wv, const float* __restrict__ bv,
    float* __restrict__ q, float* __restrict__ k, float* __restrict__ v)
{
  const int rbase = blockIdx.x * 32;
  const int tid = threadIdx.x;
  __shared__ float reps[32][128];
  __shared__ float xps[32][64];
  for (int i = tid; i < 32 * 128; i += 256)
    reps[i >> 7][i & 127] = rep[(size_t)(rbase + (i >> 7)) * 128 + (i & 127)];
  __syncthreads();
  const int col = tid & 63, rg = tid >> 6;
#pragma unroll 2
  for (int rr = 0; rr < 8; ++rr) {
    const int r = rg * 8 + rr;
    float acc = projb[col];
    for (int kk = 0; kk < 128; ++kk) acc += reps[r][kk] * projW[kk * 64 + col];
    xps[r][col] = acc;
  }
  __syncthreads();
#pragma unroll 2
  for (int rr = 0; rr < 8; ++rr) {
    const int r = rg * 8 + rr;
    float aq = bq[col], ak = bk[col], av = bv[col];
    for (int kk = 0; kk < 64; ++kk) {
      const float xv = xps[r][kk];
      aq += xv * Wq[kk * 64 + col];
      ak += xv * Wk[kk * 64 + col];
      av += xv * Wv[kk * 64 + col];
    }
    const size_t o = (size_t)(rbase + r) * 64 + col;
    q[o] = aq; k[o] = ak; v[o] = av;
  }
}

// ---------------------------------------------------------------------------
// K4: scores + rank-gate MLP + softmax + attn@v. One block per (b,n) row.
// ---------------------------------------------------------------------------
__global__ __launch_bounds__(128) void k4_attn(
    const float* __restrict__ q, const float* __restrict__ kbuf, const float* __restrict__ vbuf,
    const int* __restrict__ ranks, const float* __restrict__ rank_emb,
    const float* __restrict__ rw1W, const float* __restrict__ rw1b,
    const float* __restrict__ rw2W,
    float* __restrict__ ao)
{
  const int bn = blockIdx.x;
  const int b = bn >> 7;
  const int m = threadIdx.x;
  __shared__ float qs[64], attnw[128], red[128], aoP[2][64];
  if (m < 64) qs[m] = q[(size_t)bn * 64 + m];
  __syncthreads();
  const float* kr = kbuf + (size_t)(b * 128 + m) * 64;
  float sc = 0.f;
#pragma unroll 8
  for (int d = 0; d < 64; ++d) sc += qs[d] * kr[d];
  sc *= 0.125f;
  const int rn = ranks[bn], rm = ranks[b * 128 + m];
  int dist = rn - rm;
  if (dist < 0) dist = -dist;
  if (dist > 50) dist = 50;
  const float* er = rank_emb + dist * 32;
  float g = 0.f;
#pragma unroll
  for (int e = 0; e < 16; ++e) {
    float hs = rw1b[e];
#pragma unroll 8
    for (int i2 = 0; i2 < 32; ++i2) hs += er[i2] * rw1W[i2 * 16 + e];
    g += fmaxf(hs, 0.f) * rw2W[e];
  }
  const float smv = sc * sig_(g);
  red[m] = smv;
  __syncthreads();
  for (int sft = 64; sft > 0; sft >>= 1) {
    if (m < sft) red[m] = fmaxf(red[m], red[m + sft]);
    __syncthreads();
  }
  const float mx = red[0];
  __syncthreads();
  const float e = __expf(smv - mx);
  red[m] = e;
  __syncthreads();
  for (int sft = 64; sft > 0; sft >>= 1) {
    if (m < sft) red[m] += red[m + sft];
    __syncthreads();
  }
  attnw[m] = e / red[0];
  __syncthreads();
  const int d = m & 63, half = m >> 6;
  float acc = 0.f;
  for (int mm = half * 64; mm < half * 64 + 64; ++mm)
    acc += attnw[mm] * vbuf[(size_t)(b * 128 + mm) * 64 + d];
  aoP[half][d] = acc;
  __syncthreads();
  if (m < 64) ao[(size_t)bn * 64 + m] = aoP[0][m] + aoP[1][m];
}

// ---------------------------------------------------------------------------
// K5: ff = LN(relu(ao@ff1+b)@ff2+b) ; out = sigmoid(relu(ff@sp1+b)@sp2+b).
// ---------------------------------------------------------------------------
__global__ __launch_bounds__(128) void k5_ffout(
    const float* __restrict__ ao,
    const float* __restrict__ ff1W, const float* __restrict__ ff1b,
    const float* __restrict__ ff2W, const float* __restrict__ ff2b,
    const float* __restrict__ ln2g, const float* __restrict__ ln2b,
    const float* __restrict__ sp1W, const float* __restrict__ sp1b,
    const float* __restrict__ sp2W, const float* __restrict__ sp2b,
    float* __restrict__ out)
{
  const int row = blockIdx.x;
  const int tid = threadIdx.x;
  __shared__ float aos[64], hid[128], ffs[64], red[128], h2b[32];
  if (tid < 64) aos[tid] = ao[(size_t)row * 64 + tid];
  __syncthreads();
  float hv = ff1b[tid];
  for (int dd = 0; dd < 64; ++dd) hv += aos[dd] * ff1W[dd * 128 + tid];
  hid[tid] = fmaxf(hv, 0.f);
  __syncthreads();
  float yv = 0.f;
  if (tid < 64) {
    yv = ff2b[tid];
    for (int h2 = 0; h2 < 128; ++h2) yv += hid[h2] * ff2W[h2 * 64 + tid];
  }
  red[tid] = (tid < 64) ? yv : 0.f;
  __syncthreads();
  for (int sft = 64; sft > 0; sft >>= 1) {
    if (tid < sft) red[tid] += red[tid + sft];
    __syncthreads();
  }
  const float mean = red[0] * (1.f / 64.f);
  __syncthreads();
  {
    const float d2 = (tid < 64) ? (yv - mean) : 0.f;
    red[tid] = d2 * d2;
  }
  __syncthreads();
  for (int sft = 64; sft > 0; sft >>= 1) {
    if (tid < sft) red[tid] += red[tid + sft];
    __syncthreads();
  }
  const float var = red[0] * (1.f / 64.f);
  __syncthreads();
  if (tid < 64) ffs[tid] = (yv - mean) * rsqrtf(var + 1e-5f) * ln2g[tid] + ln2b[tid];
  __syncthreads();
  if (tid < 32) {
    float h2v = sp1b[tid];
    for (int c = 0; c < 64; ++c) h2v += ffs[c] * sp1W[c * 32 + tid];
    h2b[tid] = fmaxf(h2v, 0.f);
  }
  __syncthreads();
  if (tid == 0) {
    float o = sp2b[0];
#pragma unroll
    for (int e2 = 0; e2 < 32; ++e2) o += h2b[e2] * sp2W[e2];
    out[row] = sig_(o);
  }
}

}  // namespace

extern "C" void kernel_launch(void* const* d_in, const int* in_sizes, int n_in,
                              void* d_out, int out_size, void* d_ws, size_t ws_size,
                              hipStream_t stream)
{
  const float* x      = (const float*)d_in[0];
  const int*   ranks  = (const int*)  d_in[1];
  const float* Wih0   = (const float*)d_in[2];
  const float* Whh0   = (const float*)d_in[3];
  const float* bih0   = (const float*)d_in[4];
  const float* bhh0   = (const float*)d_in[5];
  const float* Wih1   = (const float*)d_in[6];
  const float* Whh1   = (const float*)d_in[7];
  const float* bih1   = (const float*)d_in[8];
  const float* bhh1   = (const float*)d_in[9];
  const float* attn_w = (const float*)d_in[10];
  const float* W1     = (const float*)d_in[11];
  const float* W2     = (const float*)d_in[12];
  const float* ln1g   = (const float*)d_in[13];
  const float* ln1b   = (const float*)d_in[14];
  const float* projW  = (const float*)d_in[15];
  const float* projb  = (const float*)d_in[16];
  const float* Wq     = (const float*)d_in[17];
  const float* bq     = (const float*)d_in[18];
  const float* Wk     = (const float*)d_in[19];
  const float* bk     = (const float*)d_in[20];
  const float* Wv     = (const float*)d_in[21];
  const float* bv     = (const float*)d_in[22];
  const float* remb   = (const float*)d_in[23];
  const float* rw1W   = (const float*)d_in[24];
  const float* rw1b   = (const float*)d_in[25];
  const float* rw2W   = (const float*)d_in[26];
  const float* ff1W   = (const float*)d_in[27];
  const float* ff1b   = (const float*)d_in[28];
  const float* ff2W   = (const float*)d_in[29];
  const float* ff2b   = (const float*)d_in[30];
  const float* ln2g   = (const float*)d_in[31];
  const float* ln2b   = (const float*)d_in[32];
  const float* sp1W   = (const float*)d_in[33];
  const float* sp1b   = (const float*)d_in[34];
  const float* sp2W   = (const float*)d_in[35];
  const float* sp2b   = (const float*)d_in[36];
  float* out = (float*)d_out;

  char* ws = (char*)d_ws;
  unsigned short* hist = (unsigned short*)ws;            // 4096*96*128 bf16 = 96 MB
  size_t off = (size_t)4096 * 96 * 128 * 2;
  float* rep = (float*)(ws + off); off += (size_t)4096 * 128 * 4;
  float* qb  = (float*)(ws + off); off += (size_t)4096 * 64 * 4;
  float* kb  = (float*)(ws + off); off += (size_t)4096 * 64 * 4;
  float* vb  = (float*)(ws + off); off += (size_t)4096 * 64 * 4;
  float* aob = (float*)(ws + off); off += (size_t)4096 * 64 * 4;

  k1_lstm_mfma<<<dim3(256), dim3(512), 0, stream>>>(
      x, Wih0, Whh0, bih0, bhh0, Wih1, Whh1, bih1, bhh1, hist);
  k2_pool<<<dim3(4096), dim3(256), 0, stream>>>(
      (const __hip_bfloat16*)hist, attn_w, W1, W2, ln1g, ln1b, rep);
  k3_qkv<<<dim3(128), dim3(256), 0, stream>>>(
      rep, projW, projb, Wq, bq, Wk, bk, Wv, bv, qb, kb, vb);
  k4_attn<<<dim3(4096), dim3(128), 0, stream>>>(
      qb, kb, vb, ranks, remb, rw1W, rw1b, rw2W, aob);
  k5_ffout<<<dim3(4096), dim3(128), 0, stream>>>(
      aob, ff1W, ff1b, ff2W, ff2b, ln2g, ln2b, sp1W, sp1b, sp2W, sp2b, out);
}